// Round 8
// baseline (69.730 us; speedup 1.0000x reference)
//
#include <hip/hip_runtime.h>
#include <hip/hip_bf16.h>

// Problem constants
#define NBATCH 256
#define NC 273     // C_IN (K)
#define ND 273     // C_OUT (M)
#define NT 360     // T (N)
#define NSUB 128

// GEMM tiling: one block = full D (288 padded) x 120 t-columns (3 tiles cover 360)
#define THREADS 512
#define BM 288
#define BN 128     // LDS cols (120 valid + 8 clamp-pad)
#define BNV 120
#define BK 32
#define LDK 40     // padded LDS row stride (elements) -> 80 B rows
#define KITERS 9   // ceil(273/32)

// wT (bf16, transposed w) layout in d_ws: [NSUB][288 d-rows][288 c-cols]
// c in [273,288) zero-filled for d<273 -> K-tail needs no masking.
#define WT_LD 288
#define WT_SUBJ (288 * 288)
#define WT_BYTES ((size_t)NSUB * WT_SUBJ * 2)

typedef __bf16 bf16_t;
typedef bf16_t bf16x4 __attribute__((ext_vector_type(4)));
typedef bf16_t bf16x8 __attribute__((ext_vector_type(8)));
typedef float  f32x4  __attribute__((ext_vector_type(4)));

// Raw barrier with NO vmcnt drain: LDS ops fenced manually with lgkmcnt(0);
// outstanding global loads stay in flight across the barrier.
#define LDS_FENCE_BARRIER()                                   \
    do {                                                      \
        asm volatile("s_waitcnt lgkmcnt(0)" ::: "memory");    \
        __builtin_amdgcn_s_barrier();                         \
    } while (0)

// ---- pre-pass: w[s][c][d] fp32 -> wT[s][d][c] bf16 (LDS-tiled transpose) ----
__global__ __launch_bounds__(256) void conv_w(const float* __restrict__ w,
                                              bf16_t* __restrict__ wT) {
    const int bid  = blockIdx.x;       // 128 subjects x 25 tiles
    const int s    = bid / 25;
    const int tile = bid % 25;
    const int c0   = (tile / 5) * 64;
    const int d0   = (tile % 5) * 64;
    const int tx   = threadIdx.x & 63;
    const int ty   = threadIdx.x >> 6; // 0..3

    __shared__ float t[64][65];
    const float* __restrict__ wsrc = w + (size_t)s * NC * ND;
#pragma unroll
    for (int j = 0; j < 16; ++j) {
        const int row = ty + j * 4;           // c-local
        const int c = c0 + row, d = d0 + tx;  // read coalesced along d
        t[row][tx] = (c < NC && d < ND) ? wsrc[c * ND + d] : 0.f;
    }
    __syncthreads();
    bf16_t* __restrict__ wdst = wT + (size_t)s * WT_SUBJ;
#pragma unroll
    for (int j = 0; j < 16; ++j) {
        const int row = ty + j * 4;           // d-local
        const int d = d0 + row, c = c0 + tx;  // write coalesced along c
        if (d < ND && c < WT_LD)
            wdst[d * WT_LD + c] = (bf16_t)t[tx][row];
    }
}

// ---- main GEMM ----
template<bool BF16W>
__global__ __launch_bounds__(THREADS, 2) void subject_gemm(
    const float*  __restrict__ x,        // [B, C, T]
    const int*    __restrict__ subjects, // [B]
    const float*  __restrict__ w,        // [S, C, D] (fallback path)
    const bf16_t* __restrict__ wT,       // [S, 288, 288] bf16 (main path)
    float*        __restrict__ out)      // [B, D, T]
{
    // 768 blocks = 8 XCDs x 96 slots; keep a sample's 3 t-tiles on one XCD.
    const int raw  = blockIdx.x;
    const int xcd  = raw & 7;
    const int slot = raw >> 3;          // 0..95
    const int b    = xcd * 32 + slot / 3;
    const int tt   = slot % 3;
    const int t0   = tt * BNV;
    const int s    = subjects[b];

    const float*  __restrict__ xb  = x  + (size_t)b * NC * NT;
    const float*  __restrict__ wsf = w  + (size_t)s * NC * ND;
    const bf16_t* __restrict__ wsb = wT + (size_t)s * WT_SUBJ;

    // Double-buffered LDS: 2 x (288*40 + 128*40) bf16 = 66560 B
    __shared__ __align__(16) bf16_t As[2][BM * LDK]; // [buf][d][k]
    __shared__ __align__(16) bf16_t Bs[2][BN * LDK]; // [buf][t][k]

    const int tid   = threadIdx.x;
    const int lane  = tid & 63;
    const int wid   = tid >> 6;   // 0..7
    const int wm    = wid >> 2;   // D half: 144 rows
    const int wn    = wid & 3;    // T quarter: 32 cols
    const int l16   = lane & 15;
    const int khalf = lane >> 4;  // 0..3

    // A: 2304 bf16x4-cells; cell i = tid + 512*j: kq = i&7, d = i>>3
    // (consecutive lanes read consecutive 8B within a wT row -> full 64B lines)
    int offA[5], gA[5];
#pragma unroll
    for (int j = 0; j < 5; ++j) {
        const int i  = tid + THREADS * j;
        const int ii = (i < 2304) ? i : 2303;
        const int kq = ii & 7;
        const int d  = ii >> 3;
        offA[j] = d * LDK + kq * 4;
        gA[j]   = BF16W ? (d * WT_LD + kq * 4)   // + kk at load (bf16 elems)
                        : (kq * 4 * ND + d);     // + kk*ND at load (fp32 elems)
    }
    // B: 1024 cells = (t 0..127) x (kq 0..7); i = tid + 512*j, j=0..1
    int offB[2], gB[2];
#pragma unroll
    for (int j = 0; j < 2; ++j) {
        const int i  = tid + THREADS * j;
        const int t  = i & (BN - 1);
        const int kq = i >> 7;
        const int tc = (t < BNV) ? t : (BNV - 1);   // clamp pad cols (masked at store)
        offB[j] = t * LDK + kq * 4;
        gB[j]   = kq * 4 * NT + t0 + tc;
    }
    const bool haveJ4 = (tid < 2304 - 4 * THREADS); // tid < 256, wave-uniform

    // NAMED depth-2 staging sets (even/odd tiles) -- never runtime-indexed.
    bf16x4 aEv[5], aOd[5];
    float  bEv[2][4], bOd[2][4];

    // A load: bf16 path is unmasked for ALL tiles (c-pad zeros kill the K-tail;
    // d-pad rows are garbage masked at store). kk=256 -> c<=287 < 288 in-row.
    auto loadA = [&](bf16x4 (&r)[5], int kk) {
        if constexpr (BF16W) {
#pragma unroll
            for (int j = 0; j < 4; ++j)
                r[j] = *(const bf16x4*)&wsb[gA[j] + kk];
            if (haveJ4)
                r[4] = *(const bf16x4*)&wsb[gA[4] + kk];
        } else {
            // emergency fp32 path: always masked (c>=NC or d>=ND -> 0)
#pragma unroll
            for (int j = 0; j < 5; ++j) {
                if (j == 4 && !haveJ4) break;
                const int i  = tid + THREADS * j;
                const int ii = (i < 2304) ? i : 2303;
                const int kq = ii & 7;
                const int d  = ii >> 3;
#pragma unroll
                for (int u = 0; u < 4; ++u) {
                    const int c = kk + kq * 4 + u;
                    const float f = (c < NC && d < ND) ? wsf[c * ND + d] : 0.f;
                    r[j][u] = (bf16_t)f;
                }
            }
        }
    };
    auto loadB = [&](float (&r)[2][4], int kk) {
        const int base = kk * NT;
#pragma unroll
        for (int j = 0; j < 2; ++j)
#pragma unroll
            for (int u = 0; u < 4; ++u)
                r[j][u] = xb[base + gB[j] + u * NT];
    };
    auto loadB_tail = [&](float (&r)[2][4]) {
#pragma unroll
        for (int j = 0; j < 2; ++j) {
            const int i  = tid + THREADS * j;
            const int t  = i & (BN - 1);
            const int kq = i >> 7;
            const int col = t0 + ((t < BNV) ? t : (BNV - 1));
#pragma unroll
            for (int u = 0; u < 4; ++u) {
                const int c  = 256 + kq * 4 + u;
                const int cc = (c < NC) ? c : (NC - 1);  // clamp addr; killed by A zeros
                r[j][u] = xb[cc * NT + col];
            }
        }
    };
    auto stage = [&](const bf16x4 (&rA)[5], const float (&rB)[2][4],
                     bf16_t* dA, bf16_t* dB) {
#pragma unroll
        for (int j = 0; j < 4; ++j)
            *(bf16x4*)&dA[offA[j]] = rA[j];
        if (haveJ4)
            *(bf16x4*)&dA[offA[4]] = rA[4];
#pragma unroll
        for (int j = 0; j < 2; ++j) {
            bf16x4 v;
#pragma unroll
            for (int u = 0; u < 4; ++u) v[u] = (bf16_t)rB[j][u];
            *(bf16x4*)&dB[offB[j]] = v;
        }
    };

    f32x4 acc[9][2];
#pragma unroll
    for (int m = 0; m < 9; ++m)
#pragma unroll
        for (int n = 0; n < 2; ++n)
            acc[m][n] = (f32x4){0.f, 0.f, 0.f, 0.f};

    // ---- prologue: tiles 0 (->Ev) and 1 (->Od) in flight; tile 0 staged ----
    loadA(aEv, 0);       loadB(bEv, 0);
    loadA(aOd, BK);      loadB(bOd, BK);
    stage(aEv, bEv, &As[0][0], &Bs[0][0]);   // counted vmcnt: tile1 stays in flight
    LDS_FENCE_BARRIER();

    // ---- main loop, manually unrolled x2 (static buffer choice) ----
#pragma unroll
    for (int p = 0; p < 4; ++p) {
        {   // even iter it0 = 2p: reads LDS0, stages Od -> LDS1
            const int it0 = 2 * p;
            bf16x8 af[9], bfr[2];
#pragma unroll
            for (int n = 0; n < 2; ++n)
                bfr[n] = *(const bf16x8*)&Bs[0][(wn * 32 + n * 16 + l16) * LDK + khalf * 8];
#pragma unroll
            for (int m = 0; m < 9; ++m)
                af[m] = *(const bf16x8*)&As[0][(wm * 144 + m * 16 + l16) * LDK + khalf * 8];

            // prefetch even tile it0+2 into Ev
            if (it0 + 2 <= KITERS - 1) {
                loadA(aEv, (it0 + 2) * BK);
                if (it0 + 2 <= KITERS - 2) loadB(bEv, (it0 + 2) * BK);
                else                       loadB_tail(bEv);
            }
            stage(aOd, bOd, &As[1][0], &Bs[1][0]);
            LDS_FENCE_BARRIER();

#pragma unroll
            for (int m = 0; m < 9; ++m)
#pragma unroll
                for (int n = 0; n < 2; ++n)
                    acc[m][n] = __builtin_amdgcn_mfma_f32_16x16x32_bf16(af[m], bfr[n], acc[m][n], 0, 0, 0);
        }
        {   // odd iter it1 = 2p+1: reads LDS1, stages Ev -> LDS0
            const int it1 = 2 * p + 1;
            bf16x8 af[9], bfr[2];
#pragma unroll
            for (int n = 0; n < 2; ++n)
                bfr[n] = *(const bf16x8*)&Bs[1][(wn * 32 + n * 16 + l16) * LDK + khalf * 8];
#pragma unroll
            for (int m = 0; m < 9; ++m)
                af[m] = *(const bf16x8*)&As[1][(wm * 144 + m * 16 + l16) * LDK + khalf * 8];

            // prefetch odd tile it1+2 into Od (it1+2 in {3,5,7,9}; 9 -> none)
            if (it1 + 2 <= KITERS - 2) {
                loadA(aOd, (it1 + 2) * BK);
                loadB(bOd, (it1 + 2) * BK);
            }
            stage(aEv, bEv, &As[0][0], &Bs[0][0]);
            LDS_FENCE_BARRIER();

#pragma unroll
            for (int m = 0; m < 9; ++m)
#pragma unroll
                for (int n = 0; n < 2; ++n)
                    acc[m][n] = __builtin_amdgcn_mfma_f32_16x16x32_bf16(af[m], bfr[n], acc[m][n], 0, 0, 0);
        }
    }
    {   // final iter (it = 8, even): tile 8 is in LDS0
        bf16x8 af[9], bfr[2];
#pragma unroll
        for (int n = 0; n < 2; ++n)
            bfr[n] = *(const bf16x8*)&Bs[0][(wn * 32 + n * 16 + l16) * LDK + khalf * 8];
#pragma unroll
        for (int m = 0; m < 9; ++m)
            af[m] = *(const bf16x8*)&As[0][(wm * 144 + m * 16 + l16) * LDK + khalf * 8];
#pragma unroll
        for (int m = 0; m < 9; ++m)
#pragma unroll
            for (int n = 0; n < 2; ++n)
                acc[m][n] = __builtin_amdgcn_mfma_f32_16x16x32_bf16(af[m], bfr[n], acc[m][n], 0, 0, 0);
    }

    // Epilogue: C/D layout col(t)=lane&15, row(d)=(lane>>4)*4+reg (verified R1-R7)
    float* __restrict__ ob = out + (size_t)b * ND * NT;
#pragma unroll
    for (int m = 0; m < 9; ++m) {
#pragma unroll
        for (int n = 0; n < 2; ++n) {
            const int tc = wn * 32 + n * 16 + l16;
            const int gt = t0 + tc;
#pragma unroll
            for (int rg = 0; rg < 4; ++rg) {
                const int d = wm * 144 + m * 16 + khalf * 4 + rg;
                if (d < ND && tc < BNV)
                    ob[(size_t)d * NT + gt] = acc[m][n][rg];
            }
        }
    }
}

extern "C" void kernel_launch(void* const* d_in, const int* in_sizes, int n_in,
                              void* d_out, int out_size, void* d_ws, size_t ws_size,
                              hipStream_t stream) {
    const float* x        = (const float*)d_in[0];
    const int*   subjects = (const int*)d_in[1];
    const float* w        = (const float*)d_in[2];
    float*       out      = (float*)d_out;
    bf16_t*      wT       = (bf16_t*)d_ws;

    const int nblocks = NBATCH * 3; // 768 = 8 XCDs * 96; 3 t-tiles per sample

    if (ws_size >= WT_BYTES) {
        conv_w<<<NSUB * 25, 256, 0, stream>>>(w, wT);
        subject_gemm<true><<<nblocks, THREADS, 0, stream>>>(x, subjects, w, wT, out);
    } else {
        subject_gemm<false><<<nblocks, THREADS, 0, stream>>>(x, subjects, w, wT, out);
    }
}